// Round 1
// baseline (620.527 us; speedup 1.0000x reference)
//
#include <hip/hip_runtime.h>
#include <stdint.h>
#include <math.h>

// ---------------------------------------------------------------------------
// EstimateNorm: Umeyama best-of-5 template fit + affine warps.
// Outputs (concat, float32):
//   o0 = 0        : xs            (N,5,2)        10*N
//   o1 = 10N      : IM_composed   (N,2,3)         6*N
//   o2 = 16N      : imgs_u8 NHWC  (N,224,224,3)  150528*N   (uint8 values as f32)
//   o3 = 150544N  : t192 NCHW     (N,3,192,192)  110592*N
//   o4 = 261136N  : M             (N,2,3)         6*N
// Workspace: IM per face (6N floats) + t224 float NCHW (150528N floats)
// ---------------------------------------------------------------------------

__device__ const double g_src[5][5][2] = {
  {{103.284,100.23},{115.234,99.98},{71.48,138.014},{102.314,178.1},{114.05,179.404}},
  {{90.062,100.236},{131.136,101.744},{79.354,136.222},{90.354,172.38},{128.492,173.516}},
  {{79.46,102.276},{144.54,102.276},{112.0,136.986},{84.926,174.02},{139.074,174.02}},
  {{93.69,101.744},{134.764,100.236},{145.474,136.222},{96.334,173.516},{134.472,172.38}},
  {{109.592,99.98},{121.542,100.23},{153.346,138.014},{110.776,179.404},{122.514,178.1}}
};

__global__ void estimate_kernel(const float* __restrict__ xs,
                                float* __restrict__ out,
                                float* __restrict__ ws_im, int N) {
  int n = blockIdx.x * blockDim.x + threadIdx.x;
  if (n >= N) return;

  // output 0: passthrough of xs
  #pragma unroll
  for (int i = 0; i < 10; i++) out[(size_t)n * 10 + i] = xs[(size_t)n * 10 + i];

  double px[5], py[5];
  #pragma unroll
  for (int p = 0; p < 5; p++) {
    px[p] = (double)xs[n * 10 + 2 * p];
    py[p] = (double)xs[n * 10 + 2 * p + 1];
  }
  double smx = 0.0, smy = 0.0;
  #pragma unroll
  for (int p = 0; p < 5; p++) { smx += px[p]; smy += py[p]; }
  smx *= 0.2; smy *= 0.2;
  double sdx[5], sdy[5], var_sum = 0.0;
  #pragma unroll
  for (int p = 0; p < 5; p++) {
    sdx[p] = px[p] - smx; sdy[p] = py[p] - smy;
    var_sum += sdx[p] * sdx[p] + sdy[p] * sdy[p];
  }
  var_sum *= 0.2;

  double bestE = 1e300;
  double bM[6] = {0, 0, 0, 0, 0, 0};

  for (int k = 0; k < 5; k++) {
    double dmx = 0.0, dmy = 0.0;
    #pragma unroll
    for (int p = 0; p < 5; p++) { dmx += g_src[k][p][0]; dmy += g_src[k][p][1]; }
    dmx *= 0.2; dmy *= 0.2;

    double A00 = 0, A01 = 0, A10 = 0, A11 = 0;
    #pragma unroll
    for (int p = 0; p < 5; p++) {
      double ddx = g_src[k][p][0] - dmx;
      double ddy = g_src[k][p][1] - dmy;
      A00 += ddx * sdx[p]; A01 += ddx * sdy[p];
      A10 += ddy * sdx[p]; A11 += ddy * sdy[p];
    }
    A00 *= 0.2; A01 *= 0.2; A10 *= 0.2; A11 *= 0.2;

    double detA = A00 * A11 - A01 * A10;
    double d1 = (detA > 0.0) ? 1.0 : ((detA < 0.0) ? -1.0 : 0.0);

    double E = (A00 + A11) * 0.5, F = (A00 - A11) * 0.5;
    double G = (A10 + A01) * 0.5, H = (A10 - A01) * 0.5;
    double Q = hypot(E, H), Rr = hypot(F, G);
    double sxv = Q + Rr, syv = Q - Rr;
    double a1 = atan2(G, F), a2 = atan2(H, E);
    double beta = (a2 - a1) * 0.5, gamma = (a2 + a1) * 0.5;
    double cg = cos(gamma), sg = sin(gamma);
    double cb = cos(beta),  sb = sin(beta);
    double sgn = (syv < 0.0) ? -1.0 : 1.0;
    // Vt with row1 scaled by sgn
    double Vt00 = cb, Vt01 = -sb, Vt10 = sb * sgn, Vt11 = cb * sgn;
    // R = U diag(1, d1) Vt ; U = [[cg,-sg],[sg,cg]]
    double R00 = cg * Vt00 - sg * d1 * Vt10;
    double R01 = cg * Vt01 - sg * d1 * Vt11;
    double R10 = sg * Vt00 + cg * d1 * Vt10;
    double R11 = sg * Vt01 + cg * d1 * Vt11;
    double scale = (sxv + fabs(syv) * d1) / var_sum;
    double m00 = scale * R00, m01 = scale * R01;
    double m10 = scale * R10, m11 = scale * R11;
    double t0 = dmx - (m00 * smx + m01 * smy);
    double t1 = dmy - (m10 * smx + m11 * smy);

    double e = 0.0;
    #pragma unroll
    for (int p = 0; p < 5; p++) {
      double rx = m00 * px[p] + m01 * py[p] + t0 - g_src[k][p][0];
      double ry = m10 * px[p] + m11 * py[p] + t1 - g_src[k][p][1];
      e += sqrt(rx * rx + ry * ry);
    }
    if (e < bestE) {
      bestE = e;
      bM[0] = m00; bM[1] = m01; bM[2] = t0;
      bM[3] = m10; bM[4] = m11; bM[5] = t1;
    }
  }

  size_t o1 = (size_t)10 * N;
  size_t o4 = (size_t)261136 * N;

  // output 4: M
  #pragma unroll
  for (int i = 0; i < 6; i++) out[o4 + (size_t)n * 6 + i] = (float)bM[i];

  // IM = invert(M)
  double det = bM[0] * bM[4] - bM[1] * bM[3];
  double ia = bM[4] / det, ib = -bM[1] / det;
  double ic = -bM[3] / det, idd = bM[0] / det;
  double itx = -(ia * bM[2] + ib * bM[5]);
  double ity = -(ic * bM[2] + idd * bM[5]);

  ws_im[n * 6 + 0] = (float)ia;  ws_im[n * 6 + 1] = (float)ib;  ws_im[n * 6 + 2] = (float)itx;
  ws_im[n * 6 + 3] = (float)ic;  ws_im[n * 6 + 4] = (float)idd; ws_im[n * 6 + 5] = (float)ity;

  // output 1: IM_composed = compose(IM, PREP_INV), PREP_INV=[[1.75,0,-56],[0,1.75,-56]]
  out[o1 + (size_t)n * 6 + 0] = (float)(1.75 * ia);
  out[o1 + (size_t)n * 6 + 1] = (float)(1.75 * ib);
  out[o1 + (size_t)n * 6 + 2] = (float)(-56.0 * (ia + ib) + itx);
  out[o1 + (size_t)n * 6 + 3] = (float)(1.75 * ic);
  out[o1 + (size_t)n * 6 + 4] = (float)(1.75 * idd);
  out[o1 + (size_t)n * 6 + 5] = (float)(-56.0 * (ic + idd) + ity);
}

// Warp 1024x1024x3 (HWC) image -> per-face 224x224, write float t224 (NCHW, ws)
// and uint8-truncated values as float (NHWC, out).
__global__ void warp224_kernel(const float* __restrict__ img,
                               const float* __restrict__ IMs,
                               float* __restrict__ t224f,   // may be null
                               float* __restrict__ out_u8,
                               int N, int use_ws) {
  uint32_t idx = blockIdx.x * blockDim.x + threadIdx.x;
  uint32_t total = (uint32_t)N * 50176u;
  if (idx >= total) return;
  uint32_t x = idx % 224u;
  uint32_t t = idx / 224u;
  uint32_t y = t % 224u;
  uint32_t n = t / 224u;

  const float* IM = IMs + (size_t)n * 6;
  float gx = (float)x, gy = (float)y;
  float sx = IM[0] * gx + IM[1] * gy + IM[2];
  float sy = IM[3] * gx + IM[4] * gy + IM[5];

  float x0f = floorf(sx), y0f = floorf(sy);
  float fx = sx - x0f, fy = sy - y0f;
  int x0 = (int)x0f, y0 = (int)y0f;
  int x1 = x0 + 1, y1 = y0 + 1;
  bool vx0 = (x0 >= 0) & (x0 < 1024), vx1 = (x1 >= 0) & (x1 < 1024);
  bool vy0 = (y0 >= 0) & (y0 < 1024), vy1 = (y1 >= 0) & (y1 < 1024);
  int x0c = min(max(x0, 0), 1023), x1c = min(max(x1, 0), 1023);
  int y0c = min(max(y0, 0), 1023), y1c = min(max(y1, 0), 1023);
  float w00 = (1.0f - fx) * (1.0f - fy) * (float)(vx0 & vy0);
  float w10 = fx * (1.0f - fy)          * (float)(vx1 & vy0);
  float w01 = (1.0f - fx) * fy          * (float)(vx0 & vy1);
  float w11 = fx * fy                   * (float)(vx1 & vy1);

  size_t b00 = ((size_t)y0c * 1024 + x0c) * 3;
  size_t b10 = ((size_t)y0c * 1024 + x1c) * 3;
  size_t b01 = ((size_t)y1c * 1024 + x0c) * 3;
  size_t b11 = ((size_t)y1c * 1024 + x1c) * 3;

  #pragma unroll
  for (int c = 0; c < 3; c++) {
    float v = img[b00 + c] * w00 + img[b10 + c] * w10 +
              img[b01 + c] * w01 + img[b11 + c] * w11;
    if (use_ws) t224f[(((size_t)n * 3 + c) * 224 + y) * 224 + x] = v;
    out_u8[(size_t)idx * 3 + c] = (float)(unsigned char)v;
  }
}

// Warp t224 (per-face) -> t192 with fixed transform src = 1.75*dst - 56.
__global__ void warp192_kernel(const float* __restrict__ t224f,
                               const float* __restrict__ u8src,
                               float* __restrict__ out,
                               int N, int use_ws) {
  uint32_t idx = blockIdx.x * blockDim.x + threadIdx.x;
  uint32_t total = (uint32_t)N * 110592u;
  if (idx >= total) return;
  uint32_t x = idx % 192u;
  uint32_t t = idx / 192u;
  uint32_t y = t % 192u;
  uint32_t u = t / 192u;
  uint32_t c = u % 3u;
  uint32_t n = u / 3u;

  float sx = 1.75f * (float)x - 56.0f;
  float sy = 1.75f * (float)y - 56.0f;
  float x0f = floorf(sx), y0f = floorf(sy);
  float fx = sx - x0f, fy = sy - y0f;
  int x0 = (int)x0f, y0 = (int)y0f;
  int x1 = x0 + 1, y1 = y0 + 1;
  bool vx0 = (x0 >= 0) & (x0 < 224), vx1 = (x1 >= 0) & (x1 < 224);
  bool vy0 = (y0 >= 0) & (y0 < 224), vy1 = (y1 >= 0) & (y1 < 224);
  int x0c = min(max(x0, 0), 223), x1c = min(max(x1, 0), 223);
  int y0c = min(max(y0, 0), 223), y1c = min(max(y1, 0), 223);
  float w00 = (1.0f - fx) * (1.0f - fy) * (float)(vx0 & vy0);
  float w10 = fx * (1.0f - fy)          * (float)(vx1 & vy0);
  float w01 = (1.0f - fx) * fy          * (float)(vx0 & vy1);
  float w11 = fx * fy                   * (float)(vx1 & vy1);

  float p00, p10, p01, p11;
  if (use_ws) {
    const float* plane = t224f + (((size_t)n * 3 + c) * 224) * 224;
    p00 = plane[(size_t)y0c * 224 + x0c];
    p10 = plane[(size_t)y0c * 224 + x1c];
    p01 = plane[(size_t)y1c * 224 + x0c];
    p11 = plane[(size_t)y1c * 224 + x1c];
  } else {
    const float* base = u8src + (size_t)n * 150528;
    p00 = base[((size_t)y0c * 224 + x0c) * 3 + c];
    p10 = base[((size_t)y0c * 224 + x1c) * 3 + c];
    p01 = base[((size_t)y1c * 224 + x0c) * 3 + c];
    p11 = base[((size_t)y1c * 224 + x1c) * 3 + c];
  }
  out[idx] = p00 * w00 + p10 * w10 + p01 * w01 + p11 * w11;
}

extern "C" void kernel_launch(void* const* d_in, const int* in_sizes, int n_in,
                              void* d_out, int out_size, void* d_ws, size_t ws_size,
                              hipStream_t stream) {
  const float* xs  = (const float*)d_in[0];
  const float* img = (const float*)d_in[1];
  float* out = (float*)d_out;
  float* ws  = (float*)d_ws;

  int N = in_sizes[0] / 10;  // 256

  // ws layout: [0, 6N) IM floats; t224 float NCHW at aligned offset
  size_t im_off = 0;
  size_t t224_off = (((size_t)6 * N + 127) / 128) * 128;
  size_t need_bytes = (t224_off + (size_t)150528 * N) * sizeof(float);
  int use_ws = (ws_size >= need_bytes) ? 1 : 0;

  float* ws_im  = ws + im_off;
  float* t224f  = use_ws ? (ws + t224_off) : nullptr;
  float* out_u8 = out + (size_t)16 * N;
  float* out192 = out + (size_t)150544 * N;

  // 1) per-face transform estimation (fp64, trivial cost)
  {
    int threads = 256;
    int blocks = (N + threads - 1) / threads;
    hipLaunchKernelGGL(estimate_kernel, dim3(blocks), dim3(threads), 0, stream,
                       xs, out, ws_im, N);
  }
  // 2) warp image -> t224 (ws float) + uint8-as-float output
  {
    uint32_t total = (uint32_t)N * 50176u;
    uint32_t blocks = (total + 255u) / 256u;
    hipLaunchKernelGGL(warp224_kernel, dim3(blocks), dim3(256), 0, stream,
                       img, ws_im, t224f, out_u8, N, use_ws);
  }
  // 3) warp t224 -> t192
  {
    uint32_t total = (uint32_t)N * 110592u;
    uint32_t blocks = (total + 255u) / 256u;
    hipLaunchKernelGGL(warp192_kernel, dim3(blocks), dim3(256), 0, stream,
                       t224f, out_u8, out192, N, use_ws);
  }
}

// Round 3
// 374.211 us; speedup vs baseline: 1.6582x; 1.6582x over previous
//
#include <hip/hip_runtime.h>
#include <stdint.h>
#include <math.h>

// ---------------------------------------------------------------------------
// EstimateNorm: Umeyama best-of-5 template fit + affine warps.
// Outputs (concat, float32):
//   o0 = 0        : xs            (N,5,2)        10*N
//   o1 = 10N      : IM_composed   (N,2,3)         6*N
//   o2 = 16N      : imgs_u8 NHWC  (N,224,224,3)  150528*N   (uint8 values as f32)
//   o3 = 150544N  : t192 NCHW     (N,3,192,192)  110592*N
//   o4 = 261136N  : M             (N,2,3)         6*N
//
// R3: identical to R2 except the one-line fix — warp192 writes to
// out + 150544N (was erroneously writing to out + 0, clobbering xs).
// Strategy recap: pack img -> RGBX u8 (4 MB, fits per-XCD L2) so bilinear
// taps are single 4B loads; t224 staged as packed u8 (50 MB ws); estimate
// in fp32 fused with the pack pass.
// ---------------------------------------------------------------------------

__device__ const float g_src[5][5][2] = {
  {{103.284f,100.23f},{115.234f,99.98f},{71.48f,138.014f},{102.314f,178.1f},{114.05f,179.404f}},
  {{90.062f,100.236f},{131.136f,101.744f},{79.354f,136.222f},{90.354f,172.38f},{128.492f,173.516f}},
  {{79.46f,102.276f},{144.54f,102.276f},{112.0f,136.986f},{84.926f,174.02f},{139.074f,174.02f}},
  {{93.69f,101.744f},{134.764f,100.236f},{145.474f,136.222f},{96.334f,173.516f},{134.472f,172.38f}},
  {{109.592f,99.98f},{121.542f,100.23f},{153.346f,138.014f},{110.776f,179.404f},{122.514f,178.1f}}
};

// Fused: blocks [0, packBlocks) pack img f32x3 -> RGBX u8; the block(s)
// after handle the per-face Umeyama fit.
__global__ void prep_kernel(const float* __restrict__ img,
                            const float* __restrict__ xs,
                            float* __restrict__ out,
                            float* __restrict__ ws_im,
                            uint32_t* __restrict__ pimg,
                            int N, int packBlocks) {
  if ((int)blockIdx.x < packBlocks) {
    uint32_t p = blockIdx.x * blockDim.x + threadIdx.x;  // pixel in [0, 1024^2)
    if (p < 1024u * 1024u) {
      float r = img[(size_t)p * 3 + 0];
      float g = img[(size_t)p * 3 + 1];
      float b = img[(size_t)p * 3 + 2];
      uint32_t ri = (uint32_t)(r + 0.5f);
      uint32_t gi = (uint32_t)(g + 0.5f);
      uint32_t bi = (uint32_t)(b + 0.5f);
      pimg[p] = ri | (gi << 8) | (bi << 16);
    }
    return;
  }

  int n = ((int)blockIdx.x - packBlocks) * blockDim.x + threadIdx.x;
  if (n >= N) return;

  // output 0: passthrough of xs
  #pragma unroll
  for (int i = 0; i < 10; i++) out[(size_t)n * 10 + i] = xs[(size_t)n * 10 + i];

  float px[5], py[5];
  #pragma unroll
  for (int p = 0; p < 5; p++) {
    px[p] = xs[n * 10 + 2 * p];
    py[p] = xs[n * 10 + 2 * p + 1];
  }
  float smx = 0.f, smy = 0.f;
  #pragma unroll
  for (int p = 0; p < 5; p++) { smx += px[p]; smy += py[p]; }
  smx *= 0.2f; smy *= 0.2f;
  float sdx[5], sdy[5], var_sum = 0.f;
  #pragma unroll
  for (int p = 0; p < 5; p++) {
    sdx[p] = px[p] - smx; sdy[p] = py[p] - smy;
    var_sum += sdx[p] * sdx[p] + sdy[p] * sdy[p];
  }
  var_sum *= 0.2f;

  float bestE = 1e30f;
  float bM[6] = {0, 0, 0, 0, 0, 0};

  for (int k = 0; k < 5; k++) {
    float dmx = 0.f, dmy = 0.f;
    #pragma unroll
    for (int p = 0; p < 5; p++) { dmx += g_src[k][p][0]; dmy += g_src[k][p][1]; }
    dmx *= 0.2f; dmy *= 0.2f;

    float A00 = 0, A01 = 0, A10 = 0, A11 = 0;
    #pragma unroll
    for (int p = 0; p < 5; p++) {
      float ddx = g_src[k][p][0] - dmx;
      float ddy = g_src[k][p][1] - dmy;
      A00 += ddx * sdx[p]; A01 += ddx * sdy[p];
      A10 += ddy * sdx[p]; A11 += ddy * sdy[p];
    }
    A00 *= 0.2f; A01 *= 0.2f; A10 *= 0.2f; A11 *= 0.2f;

    float detA = A00 * A11 - A01 * A10;
    float d1 = (detA > 0.f) ? 1.f : ((detA < 0.f) ? -1.f : 0.f);

    float E = (A00 + A11) * 0.5f, F = (A00 - A11) * 0.5f;
    float G = (A10 + A01) * 0.5f, H = (A10 - A01) * 0.5f;
    float Q = hypotf(E, H), Rr = hypotf(F, G);
    float sxv = Q + Rr, syv = Q - Rr;
    float a1 = atan2f(G, F), a2 = atan2f(H, E);
    float beta = (a2 - a1) * 0.5f, gamma = (a2 + a1) * 0.5f;
    float cg = cosf(gamma), sg = sinf(gamma);
    float cb = cosf(beta),  sb = sinf(beta);
    float sgn = (syv < 0.f) ? -1.f : 1.f;
    float Vt00 = cb, Vt01 = -sb, Vt10 = sb * sgn, Vt11 = cb * sgn;
    float R00 = cg * Vt00 - sg * d1 * Vt10;
    float R01 = cg * Vt01 - sg * d1 * Vt11;
    float R10 = sg * Vt00 + cg * d1 * Vt10;
    float R11 = sg * Vt01 + cg * d1 * Vt11;
    float scale = (sxv + fabsf(syv) * d1) / var_sum;
    float m00 = scale * R00, m01 = scale * R01;
    float m10 = scale * R10, m11 = scale * R11;
    float t0 = dmx - (m00 * smx + m01 * smy);
    float t1 = dmy - (m10 * smx + m11 * smy);

    float e = 0.f;
    #pragma unroll
    for (int p = 0; p < 5; p++) {
      float rx = m00 * px[p] + m01 * py[p] + t0 - g_src[k][p][0];
      float ry = m10 * px[p] + m11 * py[p] + t1 - g_src[k][p][1];
      e += sqrtf(rx * rx + ry * ry);
    }
    if (e < bestE) {
      bestE = e;
      bM[0] = m00; bM[1] = m01; bM[2] = t0;
      bM[3] = m10; bM[4] = m11; bM[5] = t1;
    }
  }

  size_t o1 = (size_t)10 * N;
  size_t o4 = (size_t)261136 * N;

  #pragma unroll
  for (int i = 0; i < 6; i++) out[o4 + (size_t)n * 6 + i] = bM[i];

  float det = bM[0] * bM[4] - bM[1] * bM[3];
  float ia = bM[4] / det, ib = -bM[1] / det;
  float ic = -bM[3] / det, idd = bM[0] / det;
  float itx = -(ia * bM[2] + ib * bM[5]);
  float ity = -(ic * bM[2] + idd * bM[5]);

  ws_im[n * 6 + 0] = ia;  ws_im[n * 6 + 1] = ib;  ws_im[n * 6 + 2] = itx;
  ws_im[n * 6 + 3] = ic;  ws_im[n * 6 + 4] = idd; ws_im[n * 6 + 5] = ity;

  out[o1 + (size_t)n * 6 + 0] = 1.75f * ia;
  out[o1 + (size_t)n * 6 + 1] = 1.75f * ib;
  out[o1 + (size_t)n * 6 + 2] = -56.f * (ia + ib) + itx;
  out[o1 + (size_t)n * 6 + 3] = 1.75f * ic;
  out[o1 + (size_t)n * 6 + 4] = 1.75f * idd;
  out[o1 + (size_t)n * 6 + 5] = -56.f * (ic + idd) + ity;
}

__device__ __forceinline__ void unpack3(uint32_t v, float& r, float& g, float& b) {
  r = (float)(v & 0xffu);
  g = (float)((v >> 8) & 0xffu);
  b = (float)((v >> 16) & 0xffu);
}

// Warp packed 1024x1024 image -> per-face 224x224.
// Writes: out_u8 (float NHWC, truncated) and packed u8 t224 (ws, rounded).
__global__ void warp224_kernel(const uint32_t* __restrict__ pimg,
                               const float* __restrict__ IMs,
                               uint32_t* __restrict__ t224p,
                               float* __restrict__ out_u8,
                               int N) {
  uint32_t idx = blockIdx.x * blockDim.x + threadIdx.x;
  uint32_t total = (uint32_t)N * 50176u;
  if (idx >= total) return;
  uint32_t x = idx % 224u;
  uint32_t t = idx / 224u;
  uint32_t y = t % 224u;
  uint32_t n = t / 224u;

  const float* IM = IMs + (size_t)n * 6;
  float gx = (float)x, gy = (float)y;
  float sx = IM[0] * gx + IM[1] * gy + IM[2];
  float sy = IM[3] * gx + IM[4] * gy + IM[5];

  float x0f = floorf(sx), y0f = floorf(sy);
  float fx = sx - x0f, fy = sy - y0f;
  int x0 = (int)x0f, y0 = (int)y0f;
  int x1 = x0 + 1, y1 = y0 + 1;
  bool vx0 = (x0 >= 0) & (x0 < 1024), vx1 = (x1 >= 0) & (x1 < 1024);
  bool vy0 = (y0 >= 0) & (y0 < 1024), vy1 = (y1 >= 0) & (y1 < 1024);
  int x0c = min(max(x0, 0), 1023), x1c = min(max(x1, 0), 1023);
  int y0c = min(max(y0, 0), 1023), y1c = min(max(y1, 0), 1023);
  float w00 = (1.0f - fx) * (1.0f - fy) * (float)(vx0 & vy0);
  float w10 = fx * (1.0f - fy)          * (float)(vx1 & vy0);
  float w01 = (1.0f - fx) * fy          * (float)(vx0 & vy1);
  float w11 = fx * fy                   * (float)(vx1 & vy1);

  uint32_t p00 = pimg[(uint32_t)y0c * 1024u + (uint32_t)x0c];
  uint32_t p10 = pimg[(uint32_t)y0c * 1024u + (uint32_t)x1c];
  uint32_t p01 = pimg[(uint32_t)y1c * 1024u + (uint32_t)x0c];
  uint32_t p11 = pimg[(uint32_t)y1c * 1024u + (uint32_t)x1c];

  float r00, g00, b00, r10, g10, b10, r01, g01, b01, r11, g11, b11;
  unpack3(p00, r00, g00, b00);
  unpack3(p10, r10, g10, b10);
  unpack3(p01, r01, g01, b01);
  unpack3(p11, r11, g11, b11);

  float vr = r00 * w00 + r10 * w10 + r01 * w01 + r11 * w11;
  float vg = g00 * w00 + g10 * w10 + g01 * w01 + g11 * w11;
  float vb = b00 * w00 + b10 * w10 + b01 * w01 + b11 * w11;

  // imgs_u8 output: truncate like .astype(uint8)
  size_t ob = (size_t)idx * 3;
  out_u8[ob + 0] = (float)(uint32_t)vr;
  out_u8[ob + 1] = (float)(uint32_t)vg;
  out_u8[ob + 2] = (float)(uint32_t)vb;

  // staged t224 for the 192-warp: round-to-nearest to minimize quant error
  uint32_t ri = (uint32_t)(vr + 0.5f);
  uint32_t gi = (uint32_t)(vg + 0.5f);
  uint32_t bi = (uint32_t)(vb + 0.5f);
  t224p[idx] = ri | (gi << 8) | (bi << 16);
}

// Warp t224 (packed u8, per-face) -> t192 NCHW with src = 1.75*dst - 56.
__global__ void warp192_kernel(const uint32_t* __restrict__ t224p,
                               float* __restrict__ out192,
                               int N) {
  uint32_t idx = blockIdx.x * blockDim.x + threadIdx.x;
  uint32_t total = (uint32_t)N * 36864u;
  if (idx >= total) return;
  uint32_t x = idx % 192u;
  uint32_t t = idx / 192u;
  uint32_t y = t % 192u;
  uint32_t n = t / 192u;

  float sx = 1.75f * (float)x - 56.0f;
  float sy = 1.75f * (float)y - 56.0f;
  float x0f = floorf(sx), y0f = floorf(sy);
  float fx = sx - x0f, fy = sy - y0f;
  int x0 = (int)x0f, y0 = (int)y0f;
  int x1 = x0 + 1, y1 = y0 + 1;
  bool vx0 = (x0 >= 0) & (x0 < 224), vx1 = (x1 >= 0) & (x1 < 224);
  bool vy0 = (y0 >= 0) & (y0 < 224), vy1 = (y1 >= 0) & (y1 < 224);
  int x0c = min(max(x0, 0), 223), x1c = min(max(x1, 0), 223);
  int y0c = min(max(y0, 0), 223), y1c = min(max(y1, 0), 223);
  float w00 = (1.0f - fx) * (1.0f - fy) * (float)(vx0 & vy0);
  float w10 = fx * (1.0f - fy)          * (float)(vx1 & vy0);
  float w01 = (1.0f - fx) * fy          * (float)(vx0 & vy1);
  float w11 = fx * fy                   * (float)(vx1 & vy1);

  const uint32_t* face = t224p + (size_t)n * 50176u;
  uint32_t p00 = face[(uint32_t)y0c * 224u + (uint32_t)x0c];
  uint32_t p10 = face[(uint32_t)y0c * 224u + (uint32_t)x1c];
  uint32_t p01 = face[(uint32_t)y1c * 224u + (uint32_t)x0c];
  uint32_t p11 = face[(uint32_t)y1c * 224u + (uint32_t)x1c];

  float r00, g00, b00, r10, g10, b10, r01, g01, b01, r11, g11, b11;
  unpack3(p00, r00, g00, b00);
  unpack3(p10, r10, g10, b10);
  unpack3(p01, r01, g01, b01);
  unpack3(p11, r11, g11, b11);

  float vr = r00 * w00 + r10 * w10 + r01 * w01 + r11 * w11;
  float vg = g00 * w00 + g10 * w10 + g01 * w01 + g11 * w11;
  float vb = b00 * w00 + b10 * w10 + b01 * w01 + b11 * w11;

  // out192 NCHW: n*110592 + c*36864 + y*192 + x
  size_t base = (size_t)n * 110592u + (size_t)y * 192u + x;
  out192[base + 0u]      = vr;
  out192[base + 36864u]  = vg;
  out192[base + 73728u]  = vb;
}

extern "C" void kernel_launch(void* const* d_in, const int* in_sizes, int n_in,
                              void* d_out, int out_size, void* d_ws, size_t ws_size,
                              hipStream_t stream) {
  const float* xs  = (const float*)d_in[0];
  const float* img = (const float*)d_in[1];
  float* out = (float*)d_out;

  int N = in_sizes[0] / 10;  // 256

  // ws layout (bytes): [0, 24N) IM floats; [8192, +4MB) packed img;
  // then packed t224 (N*50176 u32).
  char* ws = (char*)d_ws;
  float*    ws_im  = (float*)ws;
  uint32_t* pimg   = (uint32_t*)(ws + 8192);
  uint32_t* t224p  = (uint32_t*)(ws + 8192 + 4194304);

  float* out_u8  = out + (size_t)16 * N;
  float* out192  = out + (size_t)150544 * N;

  // 1) fused pack + estimate
  {
    int packBlocks = (1024 * 1024) / 256;          // 4096
    int estBlocks = (N + 255) / 256;               // 1 for N=256
    hipLaunchKernelGGL(prep_kernel, dim3(packBlocks + estBlocks), dim3(256), 0,
                       stream, img, xs, out, ws_im, pimg, N, packBlocks);
  }
  // 2) warp packed img -> out_u8 + packed t224
  {
    uint32_t total = (uint32_t)N * 50176u;
    uint32_t blocks = (total + 255u) / 256u;
    hipLaunchKernelGGL(warp224_kernel, dim3(blocks), dim3(256), 0, stream,
                       pimg, ws_im, t224p, out_u8, N);
  }
  // 3) warp packed t224 -> t192 (NCHW)
  {
    uint32_t total = (uint32_t)N * 36864u;
    uint32_t blocks = (total + 255u) / 256u;
    hipLaunchKernelGGL(warp192_kernel, dim3(blocks), dim3(256), 0, stream,
                       t224p, out192, N);
  }
}